// Round 2
// baseline (227.986 us; speedup 1.0000x reference)
//
#include <hip/hip_runtime.h>
#include <hip/hip_bf16.h>

// Problem: x (16,256,32,32) fp32, weight (8193,256) fp32 (emb = first 8192 rows).
// Rows: r = b*1024 + (h*32+w), xf[r][c] = x[b*262144 + c*1024 + (r&1023)].
// Outputs (flat fp32): xq (4194304) | loss (1) | code-as-float (16384).
//
// R11: R10's 8-phase 256^2 schedule regressed (96us, MfmaUtil 28.5, FETCH 3x)
// because 2048 blocks at 1 block/CU = 8 serial generations per CU, each paying
// a cold 64KB prologue drain + epilogue with nothing resident to overlap.
// Fix: PERSISTENT blocks. Grid = 256 (exactly 1/CU). Block p: bx = p>>3 fixed
// (A-panel L2-resident, cin constant), by = (p&7)*8 + s sweeps 8 tiles, so all
// 32 blocks of an XCD share the B-panel at each step. The chunk pipeline never
// drains: kt=3 phases stage the NEXT tile's kt=0 into buf0, and the register-
// only top-2 epilogue (no LDS) runs while those loads are in flight. Prologue
// happens once per kernel instead of 8x per CU.
// k_prep x-path: scalar 4B/lane -> float2 8B/lane (G13); LDS store stays 2-way.
// k_out unchanged.

#define N_ROWS   16384
#define KCODES   8192
#define DIM      256
#define LOSS_OFF 4194304
#define CODE_OFF 4194305
#define MARGIN_ACC 0.006f          // covers f16 noise (~8e-4 rms) + 4.9e-4 idx-mask quant

typedef _Float16 half8  __attribute__((ext_vector_type(8)));
typedef _Float16 half4v __attribute__((ext_vector_type(4)));
typedef float    float4v __attribute__((ext_vector_type(4)));
typedef float    float2v __attribute__((ext_vector_type(2)));
typedef unsigned long long u64;

__device__ __forceinline__ unsigned umax32(unsigned a, unsigned b) { return a > b ? a : b; }
__device__ __forceinline__ unsigned umin32(unsigned a, unsigned b) { return a < b ? a : b; }
__device__ __forceinline__ void gll16(const _Float16* g, _Float16* l) {
  __builtin_amdgcn_global_load_lds((const __attribute__((address_space(1))) void*)g,
                                   (__attribute__((address_space(3))) void*)l, 16, 0, 0);
}

// Copy one contiguous 8192-half (16 KB) chunk global->LDS with 512 threads:
// 2 rounds x 512 thr x 16 B. LDS dest is wave-uniform base (+lane*16 implicit).
__device__ __forceinline__ void stage16k(const _Float16* __restrict__ g, _Float16* l, int t, int w) {
  gll16(g + t * 8,        l + w * 512);
  gll16(g + 4096 + t * 8, l + 4096 + w * 512);
}

// Swizzled tile layout (xh and eh): per 128-row tile, per 64-half K-chunk,
// 16B unit u = row_local*8 + (kgrp ^ (row_local & 7)); chunk = 8192 halves.

// ---------------------------------------------------------------- fused prep (+ Sxx partials)
__global__ __launch_bounds__(256) void k_prep(const float* __restrict__ x, _Float16* __restrict__ xh,
                                              const float* __restrict__ wt, _Float16* __restrict__ eh,
                                              float* __restrict__ en2c, float* __restrict__ sxxp,
                                              double* __restrict__ dacc, unsigned* __restrict__ cnt) {
  __shared__ float lsx[128 * 65];               // x path: [n][c'] fp32, stride 65
  __shared__ __align__(16) _Float16 ls[8192];   // e path: 32 codes x 256 halves
  __shared__ float es[32];
  int t = threadIdx.x;
  int lane = t & 63, wv = t >> 6;
  int bid = blockIdx.x;
  if (bid < 512) {
    // ---- x path: 512 blocks = 128 row-tiles x 4 K-chunks
    if (bid == 0 && t == 0) { dacc[0] = 0.0; *cnt = 0u; }   // consumed only in k_out
    int blk = bid >> 2, cc = bid & 3;
    int row0 = blk * 128;
    int b    = row0 >> 10;
    int n0   = row0 & 1023;
    const float* xb = x + (size_t)b * 262144 + n0;   // xb[c*1024 + n_local]
    int c_off = t >> 6;                              // 0..3 (one c per wave per j)
    int nn    = (t & 63) * 2;                        // 0..126
    float sxx = 0.f;
    for (int j = 0; j < 16; ++j) {
      int c = cc * 64 + j * 4 + c_off;
      float2v v = *(const float2v*)&xb[(size_t)c * 1024 + nn];   // wave: 512B contiguous
      int cp = c & 63;
      sxx = fmaf(v[0], v[0], sxx);
      sxx = fmaf(v[1], v[1], sxx);
      lsx[nn * 65 + cp]       = v[0];               // bank=(2L+cp)%32 -> 2-way (free)
      lsx[(nn + 1) * 65 + cp] = v[1];
    }
    __syncthreads();
#pragma unroll
    for (int i = 0; i < 4; ++i) {                    // 1024 units = 128 rows x 8
      int unit = i * 256 + t;
      int rl = unit >> 3, p = unit & 7;
      const float* src = &lsx[rl * 65 + p * 8];
      half8 h;
#pragma unroll
      for (int k2 = 0; k2 < 8; ++k2) h[k2] = (_Float16)src[k2];
      int p7 = p ^ (rl & 7);
      *(half8*)&xh[(size_t)blk * 32768 + (size_t)cc * 8192 + (size_t)rl * 64 + p7 * 8] = h;
    }
#pragma unroll
    for (int d = 32; d; d >>= 1) sxx += __shfl_xor(sxx, d);
    __syncthreads();
    if (lane == 0) lsx[wv] = sxx;
    __syncthreads();
    if (t == 0) sxxp[bid] = lsx[0] + lsx[1] + lsx[2] + lsx[3];
  } else {
    // ---- e path: 256 blocks x 32 codes (swizzled eh)
    int blk  = bid - 512;
    int k0 = blk * 32;
    const float* wb = wt + (size_t)k0 * 256;
    for (int i = 0; i < 8; ++i) {
      int lin = i * 1024 + t * 4;                 // all lanes of a wave share lin>>8 = i*4+wv
      float4v v = *(const float4v*)&wb[lin];
      half4v h; float ss = 0.f;
#pragma unroll
      for (int j = 0; j < 4; ++j) { h[j] = (_Float16)v[j]; ss = fmaf(v[j], v[j], ss); }
      *(half4v*)&ls[lin] = h;
#pragma unroll
      for (int d = 32; d; d >>= 1) ss += __shfl_xor(ss, d);
      if (lane == 0) es[i * 4 + wv] = ss;
    }
    __syncthreads();
    size_t tb = (size_t)(k0 >> 7) * 32768;
    for (int i = 0; i < 4; ++i) {
      int u = i * 256 + t;
      int code_l = u >> 5;
      int cu = u & 31, chunk = cu >> 3, p = cu & 7;
      int kgl = k0 + code_l;
      int kg = p ^ (kgl & 7);
      half8 h = *(half8*)&ls[code_l * 256 + chunk * 64 + kg * 8];
      *(half8*)&eh[tb + (size_t)chunk * 8192 + (size_t)(kgl & 127) * 64 + p * 8] = h;
    }
    if (t < 32) en2c[k0 + t] = 32.0f - 0.5f * es[t];
  }
}

// ---------------------------------------------------------------- main GEMM: persistent 256^2, 8-wave, 8-phase [R11]
__global__ __launch_bounds__(512, 2) void k_gemm(const _Float16* __restrict__ xh, const _Float16* __restrict__ eh,
                                                 const float* __restrict__ en2c,
                                                 u64* __restrict__ top2) {
  __shared__ __align__(16) _Float16 As[2][16384];   // [buf][2 x 8192]: 256 codes x 64 halves (pre-swizzled)
  __shared__ __align__(16) _Float16 Bs[2][16384];   // [buf][2 x 8192]: 256 xrows x 64 halves
  int t    = threadIdx.x;
  int lane = t & 63, w = t >> 6;
  int wr = w >> 2, wc = w & 3;                  // wave: codes 128*wr, xrows 64*wc
  int ln15 = lane & 15, q = (lane >> 4) & 3;
  int q4 = q * 4;

  int p   = (int)blockIdx.x;                    // 256 blocks = 1/CU
  int xcd = p & 7;                              // dispatch round-robins XCDs
  int bx  = p >> 3;                             // code tile 0..31, FIXED per block

  const _Float16* Ag0 = eh + (size_t)(2 * bx) * 32768;
  const _Float16* Ag1 = Ag0 + 32768;
  const float*    cb  = &en2c[bx * 256 + wr * 128 + q4];

  float4v acc[8][4];
#pragma unroll
  for (int mi = 0; mi < 8; ++mi) {
    float4v cin = *(const float4v*)&cb[mi * 16];
#pragma unroll
    for (int ni = 0; ni < 4; ++ni) acc[mi][ni] = cin;
  }

  // prologue: stage tile (s=0, kt=0) into buf 0, drain, barrier — ONCE per kernel
  const _Float16* Bg0f = xh + (size_t)(2 * (xcd * 8)) * 32768;
  stage16k(Ag0, &As[0][0],    t, w);
  stage16k(Ag1, &As[0][8192], t, w);
  stage16k(Bg0f,         &Bs[0][0],    t, w);
  stage16k(Bg0f + 32768, &Bs[0][8192], t, w);
  asm volatile("s_waitcnt vmcnt(0)" ::: "memory");
  __builtin_amdgcn_s_barrier();

#pragma unroll 1
  for (int s = 0; s < 8; ++s) {
    int by = xcd * 8 + s;
    const _Float16* Bg0 = xh + (size_t)(2 * by) * 32768;  // this tile's B
    const _Float16* Bg1 = Bg0 + 32768;
    const _Float16* Bn0 = Bg0 + 65536;                    // next tile's B (s+1)
    const _Float16* Bn1 = Bn0 + 32768;

#pragma unroll
    for (int kt = 0; kt < 4; ++kt) {
      const int d = kt & 1;
      const _Float16* Ac = &As[d][0];
      const _Float16* Bc = &Bs[d][0];
      _Float16* An = &As[d ^ 1][0];
      _Float16* Bn = &Bs[d ^ 1][0];
      half8 bf[4];
#pragma unroll
      for (int ph = 0; ph < 4; ++ph) {
        const int ks = ph >> 1, mih = ph & 1;
        // ---- ds_read register subtile
        half8 af[4];
#pragma unroll
        for (int m2 = 0; m2 < 4; ++m2) {
          int rl = (mih * 4 + m2) * 16 + ln15;
          af[m2] = *(const half8*)&Ac[wr * 8192 + rl * 64 + (((ks * 4 + q) ^ (rl & 7)) * 8)];
        }
        if (mih == 0) {
#pragma unroll
          for (int ni = 0; ni < 4; ++ni) {
            int rb = (wc & 1) * 64 + ni * 16 + ln15;
            bf[ni] = *(const half8*)&Bc[(wc >> 1) * 8192 + rb * 64 + (((ks * 4 + q) ^ (rb & 7)) * 8)];
          }
        }
        // ---- issue 1 staging chunk into the other buffer:
        // kt<3 -> piece ph of (s, kt+1); kt==3 -> piece ph of (s+1, kt=0) into buf0
        // (safe: that buffer's readers all retired before the preceding boundary barrier)
        if (kt < 3) {
          if (ph == 0) stage16k(Ag0 + (kt + 1) * 8192, An,        t, w);
          if (ph == 1) stage16k(Ag1 + (kt + 1) * 8192, An + 8192, t, w);
          if (ph == 2) stage16k(Bg0 + (kt + 1) * 8192, Bn,        t, w);
          if (ph == 3) stage16k(Bg1 + (kt + 1) * 8192, Bn + 8192, t, w);
        } else if (s < 7) {
          if (ph == 0) stage16k(Ag0, An,        t, w);
          if (ph == 1) stage16k(Ag1, An + 8192, t, w);
          if (ph == 2) stage16k(Bn0, Bn,        t, w);
          if (ph == 3) stage16k(Bn1, Bn + 8192, t, w);
        }
        __builtin_amdgcn_s_barrier();
        asm volatile("s_waitcnt lgkmcnt(0)");
        __builtin_amdgcn_s_setprio(1);
#pragma unroll
        for (int m2 = 0; m2 < 4; ++m2)
#pragma unroll
          for (int ni = 0; ni < 4; ++ni)
            acc[mih * 4 + m2][ni] =
                __builtin_amdgcn_mfma_f32_16x16x32_f16(af[m2], bf[ni], acc[mih * 4 + m2][ni], 0, 0, 0);
        __builtin_amdgcn_s_setprio(0);
        __builtin_amdgcn_s_barrier();
      }
      if (kt < 3) {   // intra-tile boundary: kt+1's chunk (issued 1-4 phases ago) must land
        asm volatile("s_waitcnt vmcnt(0)" ::: "memory");
        __builtin_amdgcn_sched_barrier(0);
        __builtin_amdgcn_s_barrier();
      }
    }

    // ---- epilogue (register-only, no LDS): per x-row top-2 over this wave's
    // 128 codes -> direct global write. Runs while next tile's kt=0 loads fly.
#pragma unroll
    for (int ni = 0; ni < 4; ++ni) {
      unsigned hi[16], lo2[16];
#pragma unroll
      for (int mi = 0; mi < 8; ++mi)
#pragma unroll
        for (int rb = 0; rb < 4; rb += 2) {
          int j = mi * 2 + (rb >> 1);
          unsigned p0 = (__float_as_uint(acc[mi][ni][rb])     & 0xFFFFFF80u) | (unsigned)(mi * 16 + q4 + rb);
          unsigned p1 = (__float_as_uint(acc[mi][ni][rb + 1]) & 0xFFFFFF80u) | (unsigned)(mi * 16 + q4 + rb + 1);
          hi[j] = umax32(p0, p1); lo2[j] = umin32(p0, p1);
        }
#pragma unroll
      for (int st = 8; st; st >>= 1)
#pragma unroll
        for (int j = 0; j < 8; ++j) if (j < st) {
          unsigned nb = umax32(hi[j], hi[j + st]);
          unsigned ns = umax32(umin32(hi[j], hi[j + st]), umax32(lo2[j], lo2[j + st]));
          hi[j] = nb; lo2[j] = ns;
        }
      unsigned b = hi[0], sv = lo2[0];
#pragma unroll
      for (int dd = 16; dd < 64; dd <<= 1) {
        unsigned ob = __shfl_xor(b, dd);
        unsigned os = __shfl_xor(sv, dd);
        unsigned ns = umax32(umin32(b, ob), umax32(sv, os));
        b = umax32(b, ob); sv = ns;
      }
      if (q == 0) {
        int row = by * 256 + wc * 64 + ni * 16 + ln15;
        top2[(size_t)(bx * 2 + wr) * 16384 + row] = ((u64)b << 32) | sv;
      }
    }

    if (s < 7) {
      // re-init acc from en2c (L1-hot, hidden under the boundary drain)
#pragma unroll
      for (int mi = 0; mi < 8; ++mi) {
        float4v cin = *(const float4v*)&cb[mi * 16];
#pragma unroll
        for (int ni = 0; ni < 4; ++ni) acc[mi][ni] = cin;
      }
      asm volatile("s_waitcnt vmcnt(0)" ::: "memory");   // next tile's buf0 ready
      __builtin_amdgcn_sched_barrier(0);
      __builtin_amdgcn_s_barrier();
    }
  }
}

// ---------------------------------------------------------------- fused refine + gather + loss
__global__ __launch_bounds__(1024) void k_out(const u64* __restrict__ top2,
                                              const float* __restrict__ x, const float* __restrict__ w,
                                              float* __restrict__ out, const float* __restrict__ sxxp,
                                              double* __restrict__ dacc, unsigned* __restrict__ cnt) {
  __shared__ float ect[256 * 65];      // [c][r] transposed, stride 65; both phases <=2-way
  __shared__ double dpart[16];
  __shared__ unsigned oldc;
  int t    = threadIdx.x;
  int lane = t & 63, wv = t >> 6;      // 16 waves
  int blk  = blockIdx.x;               // 256 blocks x 64 rows
  int row0 = blk * 64;
  int b = row0 >> 10, n0 = row0 & 1023;

  // ---- phase 1: refine + inline gather + score contribution, 4 rows per wave
  double dsum = 0.0;
  for (int j = 0; j < 4; ++j) {
    int rl  = wv * 4 + j;
    int row = row0 + rl;
    u64 e = top2[(size_t)lane * 16384 + row];    // lane = code-tile
    unsigned hi = (unsigned)(e >> 32), lo = (unsigned)e;
    unsigned mx = hi;
#pragma unroll
    for (int d = 1; d < 64; d <<= 1) mx = umax32(mx, __shfl_xor(mx, d));
    float fm = __uint_as_float(mx & 0xFFFFFF80u);
    float th = fm - MARGIN_ACC;
    bool c0 = __uint_as_float(hi & 0xFFFFFF80u) >= th;
    bool c1 = __uint_as_float(lo & 0xFFFFFF80u) >= th;
    u64 bal0 = __ballot(c0), bal1 = __ballot(c1);
    int kbest;
    double d2c;                                  // = ||e||^2 - 2 x.e for the chosen code
    if (__popcll(bal0) + __popcll(bal1) <= 1) {
      int l0 = __ffsll((unsigned long long)__ballot(hi == mx)) - 1;
      kbest = l0 * 128 + (int)(__shfl(hi, l0) & 127u);
      d2c = 64.0 - 2.0 * (double)fm;             // quantized acc: +4.9e-4 worst-case per row
    } else {
      const float* xr = x + (size_t)b * 262144 + (row & 1023);
      float4v ex;
#pragma unroll
      for (int i = 0; i < 4; ++i) ex[i] = xr[(size_t)(lane * 4 + i) * 1024];
      double bs = 1e300; int bk = 0x7fffffff;
      for (int pass = 0; pass < 2; ++pass) {
        u64 bal = pass ? bal1 : bal0;
        unsigned src = pass ? lo : hi;
        while (bal) {
          int l = __ffsll((unsigned long long)bal) - 1;
          bal &= bal - 1;
          int kc = l * 128 + (int)(__shfl(src, l) & 127u);
          float4v wv4 = *(const float4v*)&w[(size_t)kc * DIM + lane * 4];
          double s = 0.0;
#pragma unroll
          for (int i = 0; i < 4; ++i) { double ev = (double)wv4[i]; s += ev * (ev - 2.0 * (double)ex[i]); }
#pragma unroll
          for (int d = 1; d < 64; d <<= 1) s += __shfl_xor(s, d);
          if (s < bs || (s == bs && kc < bk)) { bs = s; bk = kc; }
        }
      }
      kbest = bk;                                // all lanes agree (shuffle-reduced)
      d2c = bs;                                  // exact fp64
    }
    if (lane == 0) { out[CODE_OFF + row] = (float)kbest; dsum += d2c; }
    // inline gather: whole wave loads this row's e-vector (coalesced 256B x4)
    const float* wrow = w + (size_t)kbest * 256;
#pragma unroll
    for (int i = 0; i < 4; ++i) ect[(i * 64 + lane) * 65 + rl] = wrow[i * 64 + lane];
  }
  __syncthreads();

  // ---- phase 2: write xq (full-wave 256B txns); loss from scores, no x read
  const size_t base = (size_t)b * 262144 + n0 + lane;
  for (int j = 0; j < 16; ++j) {
    int c = wv * 16 + j;
    out[base + (size_t)c * 1024] = ect[c * 65 + lane];
  }
  if (lane == 0) dpart[wv] = dsum;
  __syncthreads();
  if (t == 0) {
    double s = 0.0;
#pragma unroll
    for (int i = 0; i < 16; ++i) s += dpart[i];
    atomicAdd(&dacc[0], s);
    __threadfence();
    oldc = atomicAdd(cnt, 1u);
  }
  __syncthreads();
  if (oldc == 255u && t < 64) {                  // last block: wave 0 finalizes
    float ps = 0.f;
#pragma unroll
    for (int i = 0; i < 8; ++i) ps += sxxp[t * 8 + i];
#pragma unroll
    for (int d = 32; d; d >>= 1) ps += __shfl_xor(ps, d);
    if (t == 0) {
      __threadfence();
      double sd2 = *(volatile double*)&dacc[0];
      out[LOSS_OFF] = (float)(1.25 * ((double)ps + sd2) / 4194304.0);
    }
  }
}

// ---------------------------------------------------------------- launch
extern "C" void kernel_launch(void* const* d_in, const int* in_sizes, int n_in,
                              void* d_out, int out_size, void* d_ws, size_t ws_size,
                              hipStream_t stream) {
  const float* x = (const float*)d_in[0];
  const float* w = (const float*)d_in[1];
  float* out = (float*)d_out;
  char* ws = (char*)d_ws;
  _Float16* xh   = (_Float16*)(ws);                 //  8,388,608 B (swizzled tiles)
  _Float16* eh   = (_Float16*)(ws + 8388608);       //  4,194,304 B (swizzled tiles)
  float*    en2c = (float*)(ws + 12582912);         //     32,768 B
  u64*      top2 = (u64*)(ws + 12615680);           //  8,388,608 B ([64 tile][16384 row] u64)
  float*    sxxp = (float*)(ws + 21004288);         //      2,048 B (512 partials)
  double*   dacc = (double*)(ws + 21006336);        //          8 B (sum d2)
  unsigned* cnt  = (unsigned*)(ws + 21006344);      //          4 B

  k_prep<<<768, 256, 0, stream>>>(x, xh, w, eh, en2c, sxxp, dacc, cnt);
  k_gemm<<<256, 512, 0, stream>>>(xh, eh, en2c, top2);
  k_out<<<256, 1024, 0, stream>>>(top2, x, w, out, sxxp, dacc, cnt);
}

// Round 3
// 184.234 us; speedup vs baseline: 1.2375x; 1.2375x over previous
//
#include <hip/hip_runtime.h>
#include <hip/hip_bf16.h>

// Problem: x (16,256,32,32) fp32, weight (8193,256) fp32 (emb = first 8192 rows).
// Rows: r = b*1024 + (h*32+w), xf[r][c] = x[b*262144 + c*1024 + (r&1023)].
// Outputs (flat fp32): xq (4194304) | loss (1) | code-as-float (16384).
//
// R12: R11 refetched the A-panel from global every tile (FETCH 205MB, L2 thrash:
// 32 distinct bx per XCD). Fix: A-panel (256 codes x 256 halves = 128 KB) lives
// in LDS for the WHOLE kernel (staged once); B streams through a 2x16KB double
// buffer in BK=32 chunks. LDS = 160 KB exactly (gfx950 max). Per-XCD B sharing:
// block p has bx=p>>3 fixed, by=(p&7)*8+s, so all 32 blocks of an XCD read the
// same B tile each step (B HBM = 8 MB once; A ~32MB L3 burst at prologue only).
// Phase: {12 ds_read_b128 | stage next B chunk (2 gll16) | lgkmcnt(0) |
// setprio(1) 32 MFMA setprio(0) | vmcnt(0) | barrier} - 1 barrier/phase,
// stage hidden under MFMA, register-only top-2 epilogue needs no drain.
// Layout change: xh/eh chunks are now 32-half (4096-half = 8KB contiguous
// granules, kg ^= (rl>>1)&3 swizzle) so BK=32 stages are linear gll16 copies.
// k_out unchanged.

#define N_ROWS   16384
#define KCODES   8192
#define DIM      256
#define LOSS_OFF 4194304
#define CODE_OFF 4194305
#define MARGIN_ACC 0.006f          // covers f16 noise (~8e-4 rms) + 4.9e-4 idx-mask quant

typedef _Float16 half8  __attribute__((ext_vector_type(8)));
typedef _Float16 half4v __attribute__((ext_vector_type(4)));
typedef float    float4v __attribute__((ext_vector_type(4)));
typedef float    float2v __attribute__((ext_vector_type(2)));
typedef unsigned long long u64;

__device__ __forceinline__ unsigned umax32(unsigned a, unsigned b) { return a > b ? a : b; }
__device__ __forceinline__ unsigned umin32(unsigned a, unsigned b) { return a < b ? a : b; }
__device__ __forceinline__ void gll16(const _Float16* g, _Float16* l) {
  __builtin_amdgcn_global_load_lds((const __attribute__((address_space(1))) void*)g,
                                   (__attribute__((address_space(3))) void*)l, 16, 0, 0);
}

// Swizzled tile layout (xh and eh): per 128-row tile: [8 chunks of 32 halves],
// chunk = 4096 halves (8 KB contiguous). Within chunk: row rl (0..127) at
// rl*32, unit kgp (0..3, 8 halves) stores source k-group kgp ^ ((rl>>1)&3).

// ---------------------------------------------------------------- fused prep (+ Sxx partials)
__global__ __launch_bounds__(256) void k_prep(const float* __restrict__ x, _Float16* __restrict__ xh,
                                              const float* __restrict__ wt, _Float16* __restrict__ eh,
                                              float* __restrict__ en2c, float* __restrict__ sxxp,
                                              double* __restrict__ dacc, unsigned* __restrict__ cnt) {
  __shared__ float lsx[128 * 65];               // x path: [n][c'] fp32, stride 65
  __shared__ __align__(16) _Float16 ls[8192];   // e path: 32 codes x 256 halves
  __shared__ float es[32];
  int t = threadIdx.x;
  int lane = t & 63, wv = t >> 6;
  int bid = blockIdx.x;
  if (bid < 512) {
    // ---- x path: 512 blocks = 128 row-tiles x 4 channel-quarters (64 ch each)
    if (bid == 0 && t == 0) { dacc[0] = 0.0; *cnt = 0u; }   // consumed only in k_out
    int blk = bid >> 2, cc = bid & 3;
    int row0 = blk * 128;
    int b    = row0 >> 10;
    int n0   = row0 & 1023;
    const float* xb = x + (size_t)b * 262144 + n0;   // xb[c*1024 + n_local]
    int c_off = t >> 6;                              // 0..3 (one c per wave per j)
    int nn    = (t & 63) * 2;                        // 0..126
    float sxx = 0.f;
    for (int j = 0; j < 16; ++j) {
      int c = cc * 64 + j * 4 + c_off;
      float2v v = *(const float2v*)&xb[(size_t)c * 1024 + nn];   // wave: 512B contiguous
      int cp = c & 63;
      sxx = fmaf(v[0], v[0], sxx);
      sxx = fmaf(v[1], v[1], sxx);
      lsx[nn * 65 + cp]       = v[0];               // 2-way bank alias (free)
      lsx[(nn + 1) * 65 + cp] = v[1];
    }
    __syncthreads();
#pragma unroll
    for (int i = 0; i < 4; ++i) {                    // 1024 units = 128 rows x 8
      int unit = i * 256 + t;
      int rl = unit >> 3, pp = unit & 7;
      int chl = pp >> 2, kgp = pp & 3;               // chunk-half, output k-group
      int kg  = kgp ^ ((rl >> 1) & 3);               // source k-group
      const float* src = &lsx[rl * 65 + chl * 32 + kg * 8];
      half8 h;
#pragma unroll
      for (int k2 = 0; k2 < 8; ++k2) h[k2] = (_Float16)src[k2];
      *(half8*)&xh[(size_t)blk * 32768 + (size_t)(cc * 2 + chl) * 4096 + (size_t)rl * 32 + kgp * 8] = h;
    }
#pragma unroll
    for (int d = 32; d; d >>= 1) sxx += __shfl_xor(sxx, d);
    __syncthreads();
    if (lane == 0) lsx[wv] = sxx;
    __syncthreads();
    if (t == 0) sxxp[bid] = lsx[0] + lsx[1] + lsx[2] + lsx[3];
  } else {
    // ---- e path: 256 blocks x 32 codes (swizzled eh)
    int blk  = bid - 512;
    int k0 = blk * 32;
    const float* wb = wt + (size_t)k0 * 256;
    for (int i = 0; i < 8; ++i) {
      int lin = i * 1024 + t * 4;                 // all lanes of a wave share lin>>8 = i*4+wv
      float4v v = *(const float4v*)&wb[lin];
      half4v h; float ss = 0.f;
#pragma unroll
      for (int j = 0; j < 4; ++j) { h[j] = (_Float16)v[j]; ss = fmaf(v[j], v[j], ss); }
      *(half4v*)&ls[lin] = h;
#pragma unroll
      for (int d = 32; d; d >>= 1) ss += __shfl_xor(ss, d);
      if (lane == 0) es[i * 4 + wv] = ss;
    }
    __syncthreads();
    size_t tb = (size_t)(k0 >> 7) * 32768;
    for (int i = 0; i < 4; ++i) {
      int u = i * 256 + t;                        // 1024 units = 32 codes x 32
      int code_l = u >> 5;
      int cu = u & 31, ch = cu >> 2, kgp = cu & 3;
      int rl = (k0 + code_l) & 127;               // row within 128-code tile
      int kg = kgp ^ ((rl >> 1) & 3);
      half8 h = *(half8*)&ls[code_l * 256 + ch * 32 + kg * 8];
      *(half8*)&eh[tb + (size_t)ch * 4096 + (size_t)rl * 32 + kgp * 8] = h;
    }
    if (t < 32) en2c[k0 + t] = 32.0f - 0.5f * es[t];
  }
}

// ---------------------------------------------------------------- main GEMM: A-panel resident in LDS [R12]
__global__ __launch_bounds__(512, 2) void k_gemm(const _Float16* __restrict__ xh, const _Float16* __restrict__ eh,
                                                 const float* __restrict__ en2c,
                                                 u64* __restrict__ top2) {
  __shared__ __align__(16) _Float16 Af[65536];      // 128 KB: A panel [wr(2)][chunk(8)][4096]
  __shared__ __align__(16) _Float16 Bb[2][8192];    // 2x16 KB: B chunk dbuf [subtile(2)][4096]
  int t    = threadIdx.x;
  int lane = t & 63, w = t >> 6;
  int wr = w >> 2, wc = w & 3;                  // wave: codes 128*wr, xrows 64*wc
  int ln15 = lane & 15, q = (lane >> 4) & 3;
  int q4 = q * 4;

  int p  = (int)blockIdx.x;                     // 256 blocks = 1/CU
  int j  = p & 7;                               // dispatch round-robins XCDs
  int bx = p >> 3;                              // code tile 0..31, FIXED per block

  const _Float16* Ae = eh + (size_t)bx * 65536; // 2 adjacent 128-code tiles, contiguous
  const float*    cb = &en2c[bx * 256 + wr * 128 + q4];

  // prologue: A panel (16 x 8KB granules) + B chunk 0 of s=0; drain once
#pragma unroll
  for (int k = 0; k < 16; ++k)
    gll16(Ae + k * 4096 + t * 8, Af + k * 4096 + w * 512);
  {
    const _Float16* B0 = xh + (size_t)(j * 8) * 65536;
    gll16(B0 + t * 8,         &Bb[0][0]    + w * 512);
    gll16(B0 + 32768 + t * 8, &Bb[0][4096] + w * 512);
  }
  asm volatile("s_waitcnt vmcnt(0)" ::: "memory");
  __builtin_amdgcn_s_barrier();

  float4v acc[8][4];
#pragma unroll 1
  for (int s = 0; s < 8; ++s) {
    const _Float16* Bt = xh + (size_t)(j * 8 + s) * 65536;   // this tile's B (2 subtiles)
#pragma unroll
    for (int mi = 0; mi < 8; ++mi) {
      float4v cin = *(const float4v*)&cb[mi * 16];
#pragma unroll
      for (int ni = 0; ni < 4; ++ni) acc[mi][ni] = cin;
    }
#pragma unroll
    for (int c = 0; c < 8; ++c) {
      // ---- ds_read frags (A from resident panel, B from landed chunk)
      half8 af[8], bf[4];
#pragma unroll
      for (int mi = 0; mi < 8; ++mi) {
        int rl = mi * 16 + ln15;
        af[mi] = *(const half8*)&Af[wr * 32768 + c * 4096 + rl * 32 + ((q ^ ((rl >> 1) & 3)) * 8)];
      }
#pragma unroll
      for (int ni = 0; ni < 4; ++ni) {
        int rb = (wc & 1) * 64 + ni * 16 + ln15;
        bf[ni] = *(const half8*)&Bb[c & 1][(wc >> 1) * 4096 + rb * 32 + ((q ^ ((rb >> 1) & 3)) * 8)];
      }
      // ---- stage next B chunk into the other buffer (c<7: chunk c+1 of s;
      // c==7: chunk 0 of s+1). Write-safe: all waves' reads of that buffer
      // retired at their lgkmcnt(0) before the previous phase's barrier.
      if (c < 7) {
        gll16(Bt + (c + 1) * 4096 + t * 8,         &Bb[(c + 1) & 1][0]    + w * 512);
        gll16(Bt + 32768 + (c + 1) * 4096 + t * 8, &Bb[(c + 1) & 1][4096] + w * 512);
      } else if (s < 7) {
        gll16(Bt + 65536 + t * 8,         &Bb[0][0]    + w * 512);
        gll16(Bt + 98304 + t * 8,         &Bb[0][4096] + w * 512);
      }
      asm volatile("s_waitcnt lgkmcnt(0)");
      __builtin_amdgcn_sched_barrier(0);
      __builtin_amdgcn_s_setprio(1);
#pragma unroll
      for (int mi = 0; mi < 8; ++mi)
#pragma unroll
        for (int ni = 0; ni < 4; ++ni)
          acc[mi][ni] = __builtin_amdgcn_mfma_f32_16x16x32_f16(af[mi], bf[ni], acc[mi][ni], 0, 0, 0);
      __builtin_amdgcn_s_setprio(0);
      asm volatile("s_waitcnt vmcnt(0)" ::: "memory");  // staged chunk landed (hid under MFMA)
      __builtin_amdgcn_s_barrier();
    }

    // ---- epilogue (register-only): per x-row top-2 over this wave's 128 codes
    // -> direct global write. No extra sync: next phase's buffer is landed, and
    // its stage target was cleared by c=7's lgkmcnt+barrier.
    int by = j * 8 + s;
#pragma unroll
    for (int ni = 0; ni < 4; ++ni) {
      unsigned hi[16], lo2[16];
#pragma unroll
      for (int mi = 0; mi < 8; ++mi)
#pragma unroll
        for (int rb = 0; rb < 4; rb += 2) {
          int jj = mi * 2 + (rb >> 1);
          unsigned p0 = (__float_as_uint(acc[mi][ni][rb])     & 0xFFFFFF80u) | (unsigned)(mi * 16 + q4 + rb);
          unsigned p1 = (__float_as_uint(acc[mi][ni][rb + 1]) & 0xFFFFFF80u) | (unsigned)(mi * 16 + q4 + rb + 1);
          hi[jj] = umax32(p0, p1); lo2[jj] = umin32(p0, p1);
        }
#pragma unroll
      for (int st = 8; st; st >>= 1)
#pragma unroll
        for (int jj = 0; jj < 8; ++jj) if (jj < st) {
          unsigned nb = umax32(hi[jj], hi[jj + st]);
          unsigned ns = umax32(umin32(hi[jj], hi[jj + st]), umax32(lo2[jj], lo2[jj + st]));
          hi[jj] = nb; lo2[jj] = ns;
        }
      unsigned b = hi[0], sv = lo2[0];
#pragma unroll
      for (int dd = 16; dd < 64; dd <<= 1) {
        unsigned ob = __shfl_xor(b, dd);
        unsigned os = __shfl_xor(sv, dd);
        unsigned ns = umax32(umin32(b, ob), umax32(sv, os));
        b = umax32(b, ob); sv = ns;
      }
      if (q == 0) {
        int row = by * 256 + wc * 64 + ni * 16 + ln15;
        top2[(size_t)(bx * 2 + wr) * 16384 + row] = ((u64)b << 32) | sv;
      }
    }
  }
}

// ---------------------------------------------------------------- fused refine + gather + loss
__global__ __launch_bounds__(1024) void k_out(const u64* __restrict__ top2,
                                              const float* __restrict__ x, const float* __restrict__ w,
                                              float* __restrict__ out, const float* __restrict__ sxxp,
                                              double* __restrict__ dacc, unsigned* __restrict__ cnt) {
  __shared__ float ect[256 * 65];      // [c][r] transposed, stride 65; both phases <=2-way
  __shared__ double dpart[16];
  __shared__ unsigned oldc;
  int t    = threadIdx.x;
  int lane = t & 63, wv = t >> 6;      // 16 waves
  int blk  = blockIdx.x;               // 256 blocks x 64 rows
  int row0 = blk * 64;
  int b = row0 >> 10, n0 = row0 & 1023;

  // ---- phase 1: refine + inline gather + score contribution, 4 rows per wave
  double dsum = 0.0;
  for (int j = 0; j < 4; ++j) {
    int rl  = wv * 4 + j;
    int row = row0 + rl;
    u64 e = top2[(size_t)lane * 16384 + row];    // lane = code-tile
    unsigned hi = (unsigned)(e >> 32), lo = (unsigned)e;
    unsigned mx = hi;
#pragma unroll
    for (int d = 1; d < 64; d <<= 1) mx = umax32(mx, __shfl_xor(mx, d));
    float fm = __uint_as_float(mx & 0xFFFFFF80u);
    float th = fm - MARGIN_ACC;
    bool c0 = __uint_as_float(hi & 0xFFFFFF80u) >= th;
    bool c1 = __uint_as_float(lo & 0xFFFFFF80u) >= th;
    u64 bal0 = __ballot(c0), bal1 = __ballot(c1);
    int kbest;
    double d2c;                                  // = ||e||^2 - 2 x.e for the chosen code
    if (__popcll(bal0) + __popcll(bal1) <= 1) {
      int l0 = __ffsll((unsigned long long)__ballot(hi == mx)) - 1;
      kbest = l0 * 128 + (int)(__shfl(hi, l0) & 127u);
      d2c = 64.0 - 2.0 * (double)fm;             // quantized acc: +4.9e-4 worst-case per row
    } else {
      const float* xr = x + (size_t)b * 262144 + (row & 1023);
      float4v ex;
#pragma unroll
      for (int i = 0; i < 4; ++i) ex[i] = xr[(size_t)(lane * 4 + i) * 1024];
      double bs = 1e300; int bk = 0x7fffffff;
      for (int pass = 0; pass < 2; ++pass) {
        u64 bal = pass ? bal1 : bal0;
        unsigned src = pass ? lo : hi;
        while (bal) {
          int l = __ffsll((unsigned long long)bal) - 1;
          bal &= bal - 1;
          int kc = l * 128 + (int)(__shfl(src, l) & 127u);
          float4v wv4 = *(const float4v*)&w[(size_t)kc * DIM + lane * 4];
          double s = 0.0;
#pragma unroll
          for (int i = 0; i < 4; ++i) { double ev = (double)wv4[i]; s += ev * (ev - 2.0 * (double)ex[i]); }
#pragma unroll
          for (int d = 1; d < 64; d <<= 1) s += __shfl_xor(s, d);
          if (s < bs || (s == bs && kc < bk)) { bs = s; bk = kc; }
        }
      }
      kbest = bk;                                // all lanes agree (shuffle-reduced)
      d2c = bs;                                  // exact fp64
    }
    if (lane == 0) { out[CODE_OFF + row] = (float)kbest; dsum += d2c; }
    // inline gather: whole wave loads this row's e-vector (coalesced 256B x4)
    const float* wrow = w + (size_t)kbest * 256;
#pragma unroll
    for (int i = 0; i < 4; ++i) ect[(i * 64 + lane) * 65 + rl] = wrow[i * 64 + lane];
  }
  __syncthreads();

  // ---- phase 2: write xq (full-wave 256B txns); loss from scores, no x read
  const size_t base = (size_t)b * 262144 + n0 + lane;
  for (int j = 0; j < 16; ++j) {
    int c = wv * 16 + j;
    out[base + (size_t)c * 1024] = ect[c * 65 + lane];
  }
  if (lane == 0) dpart[wv] = dsum;
  __syncthreads();
  if (t == 0) {
    double s = 0.0;
#pragma unroll
    for (int i = 0; i < 16; ++i) s += dpart[i];
    atomicAdd(&dacc[0], s);
    __threadfence();
    oldc = atomicAdd(cnt, 1u);
  }
  __syncthreads();
  if (oldc == 255u && t < 64) {                  // last block: wave 0 finalizes
    float ps = 0.f;
#pragma unroll
    for (int i = 0; i < 8; ++i) ps += sxxp[t * 8 + i];
#pragma unroll
    for (int d = 32; d; d >>= 1) ps += __shfl_xor(ps, d);
    if (t == 0) {
      __threadfence();
      double sd2 = *(volatile double*)&dacc[0];
      out[LOSS_OFF] = (float)(1.25 * ((double)ps + sd2) / 4194304.0);
    }
  }
}

// ---------------------------------------------------------------- launch
extern "C" void kernel_launch(void* const* d_in, const int* in_sizes, int n_in,
                              void* d_out, int out_size, void* d_ws, size_t ws_size,
                              hipStream_t stream) {
  const float* x = (const float*)d_in[0];
  const float* w = (const float*)d_in[1];
  float* out = (float*)d_out;
  char* ws = (char*)d_ws;
  _Float16* xh   = (_Float16*)(ws);                 //  8,388,608 B (swizzled tiles)
  _Float16* eh   = (_Float16*)(ws + 8388608);       //  4,194,304 B (swizzled tiles)
  float*    en2c = (float*)(ws + 12582912);         //     32,768 B
  u64*      top2 = (u64*)(ws + 12615680);           //  8,388,608 B ([64 tile][16384 row] u64)
  float*    sxxp = (float*)(ws + 21004288);         //      2,048 B (512 partials)
  double*   dacc = (double*)(ws + 21006336);        //          8 B (sum d2)
  unsigned* cnt  = (unsigned*)(ws + 21006344);      //          4 B

  k_prep<<<768, 256, 0, stream>>>(x, xh, w, eh, en2c, sxxp, dacc, cnt);
  k_gemm<<<256, 512, 0, stream>>>(xh, eh, en2c, top2);
  k_out<<<256, 1024, 0, stream>>>(top2, x, w, out, sxxp, dacc, cnt);
}